// Round 1
// baseline (901.282 us; speedup 1.0000x reference)
//
#include <hip/hip_runtime.h>

namespace {
constexpr int BB   = 64;
constexpr int CC   = 64;        // C_IN == C_OUT
constexpr int HH   = 64;
constexpr int WW   = 64;
constexpr int HW   = HH * WW;   // 4096
constexpr int CHW  = CC * HW;   // 262144
constexpr int NTOT = BB * CHW;  // 16777216

constexpr float MEM_DECAY = 0.99f;
constexpr float MEM_RESET = 0.1f;
constexpr float TH_DECAY  = 0.95f;
constexpr float TH_RESET  = 1.0f;
constexpr float TR_DECAY  = 0.95f;
constexpr float A_POS     = 0.005f;
constexpr float A_NEG     = 0.005f;
constexpr float W_CLIP    = 0.1f;
}

// ---------------------------------------------------------------------------
// K0: transpose weights [co][ci][9] -> wt [ci][co][12] (k-padded for alignment)
// ---------------------------------------------------------------------------
__global__ void k_transpose_w(const float* __restrict__ w, float* __restrict__ wt)
{
    const int i = blockIdx.x * 256 + threadIdx.x;   // 0..36863
    if (i >= CC * CC * 9) return;
    const int co = i / 576;
    const int r  = i - co * 576;
    const int ci = r / 9;
    const int k  = r - ci * 9;
    wt[(ci * CC + co) * 12 + k] = w[i];
}

// ---------------------------------------------------------------------------
// K1: fused conv3x3 (pad=1) + LIF dynamics + post-trace.
// Block: 256 threads = 4 waves; block handles (b, 4 rows y0..y0+3, all co, all x).
// Wave wv -> row y0+wv. Lane: cg=lane>>3 (co group of 8), xg=lane&7 (x group of 8).
// Each lane computes acc[8co][8x].
// LDS: input tile [6 rows][16 ci][68 x-padded], weights [16 ci][swizzled co][12].
// ---------------------------------------------------------------------------
__global__ __launch_bounds__(256, 2) void k_conv_lif(
    const float* __restrict__ xin, const float* __restrict__ wt,
    const float* __restrict__ membrane, const float* __restrict__ thresh,
    const float* __restrict__ tpost,
    float* __restrict__ o_spk, float* __restrict__ o_mem,
    float* __restrict__ o_th, float* __restrict__ o_post)
{
    __shared__ float in_lds[6 * 16 * 68];   // 26112 B
    __shared__ float w_lds[16 * 800];       // 51200 B  (off = ci*800 + co*12 + (co>>3)*4 + k)

    const int tid  = threadIdx.x;
    const int b    = blockIdx.x >> 4;
    const int y0   = (blockIdx.x & 15) << 2;
    const int wv   = tid >> 6;
    const int lane = tid & 63;
    const int cg   = lane >> 3;
    const int xg   = lane & 7;
    const int y    = y0 + wv;

    float acc[8][8];
#pragma unroll
    for (int i = 0; i < 8; ++i)
#pragma unroll
        for (int j = 0; j < 8; ++j) acc[i][j] = 0.f;

    for (int cc = 0; cc < 4; ++cc) {        // ci chunks of 16
        const int cib = cc << 4;
        __syncthreads();                    // protect LDS reuse

        // stage input rows y0-1 .. y0+4 for 16 ci, x padded [-1..66]
#pragma unroll 1
        for (int t = tid; t < 6 * 16 * 68; t += 256) {
            const int xp = t % 68;
            const int rr = (t / 68) % 6;
            const int ci = t / 408;         // 408 = 6*68
            const int gy = y0 + rr - 1;
            const int gx = xp - 1;
            float v = 0.f;
            if ((unsigned)gy < 64u && (unsigned)gx < 64u)
                v = xin[((b * CC + cib + ci) * HH + gy) * WW + gx];
            in_lds[(rr * 16 + ci) * 68 + xp] = v;
        }
        // stage weights (coalesced from pre-transposed wt), swizzled co stride
#pragma unroll 1
        for (int t = tid; t < 16 * 768; t += 256) {
            const int ci = t / 768;
            const int r  = t - ci * 768;
            const int co = r / 12;
            const int k  = r - co * 12;
            w_lds[ci * 800 + co * 12 + ((co >> 3) << 2) + k] = wt[(cib + ci) * 768 + r];
        }
        __syncthreads();

#pragma unroll 1
        for (int ci = 0; ci < 16; ++ci) {
            float inr[3][12];
#pragma unroll
            for (int dy = 0; dy < 3; ++dy) {
                const float* p = &in_lds[((wv + dy) * 16 + ci) * 68 + (xg << 3)];
                const float4 a0 = *(const float4*)(p);
                const float4 a1 = *(const float4*)(p + 4);
                const float4 a2 = *(const float4*)(p + 8);
                inr[dy][0] = a0.x;  inr[dy][1] = a0.y;  inr[dy][2]  = a0.z;  inr[dy][3]  = a0.w;
                inr[dy][4] = a1.x;  inr[dy][5] = a1.y;  inr[dy][6]  = a1.z;  inr[dy][7]  = a1.w;
                inr[dy][8] = a2.x;  inr[dy][9] = a2.y;  inr[dy][10] = a2.z;  inr[dy][11] = a2.w;
            }
            const float* wb = &w_lds[ci * 800 + cg * 100];
#pragma unroll
            for (int c = 0; c < 8; ++c) {
                const float4 w0 = *(const float4*)(wb + c * 12);
                const float4 w1 = *(const float4*)(wb + c * 12 + 4);
                const float  w8 = wb[c * 12 + 8];
                const float wk[9] = {w0.x, w0.y, w0.z, w0.w, w1.x, w1.y, w1.z, w1.w, w8};
#pragma unroll
                for (int dy = 0; dy < 3; ++dy)
#pragma unroll
                    for (int dx = 0; dx < 3; ++dx)
#pragma unroll
                        for (int xi = 0; xi < 8; ++xi)
                            acc[c][xi] = fmaf(wk[dy * 3 + dx], inr[dy][xi + dx], acc[c][xi]);
            }
        }
    }

    // LIF epilogue: 8 co rows x 8 x per lane
    const int xb = xg << 3;
#pragma unroll 1
    for (int c = 0; c < 8; ++c) {
        const int co  = (cg << 3) + c;
        const int idx = (b * CC + co) * HW + y * WW + xb;
        const float4 m0 = *(const float4*)&membrane[idx];
        const float4 m1 = *(const float4*)&membrane[idx + 4];
        const float4 t0 = *(const float4*)&thresh[idx];
        const float4 t1 = *(const float4*)&thresh[idx + 4];
        const float4 p0 = *(const float4*)&tpost[idx];
        const float4 p1 = *(const float4*)&tpost[idx + 4];
        const float mv[8] = {m0.x, m0.y, m0.z, m0.w, m1.x, m1.y, m1.z, m1.w};
        const float tv[8] = {t0.x, t0.y, t0.z, t0.w, t1.x, t1.y, t1.z, t1.w};
        const float pv[8] = {p0.x, p0.y, p0.z, p0.w, p1.x, p1.y, p1.z, p1.w};
        float sv[8], nm[8], nt[8], np[8];
#pragma unroll
        for (int j = 0; j < 8; ++j) {
            const float mem = mv[j] * MEM_DECAY + acc[c][j];
            const float s   = (mem > tv[j]) ? 1.f : 0.f;
            sv[j] = s;
            nm[j] = (s > 0.f) ? MEM_RESET : mem;
            nt[j] = (s > 0.f) ? TH_RESET : tv[j] * TH_DECAY;
            const float q = pv[j] * TR_DECAY + s;
            np[j] = fminf(fmaxf(q, 0.f), 1.f);
        }
        *(float4*)&o_spk[idx]      = make_float4(sv[0], sv[1], sv[2], sv[3]);
        *(float4*)&o_spk[idx + 4]  = make_float4(sv[4], sv[5], sv[6], sv[7]);
        *(float4*)&o_mem[idx]      = make_float4(nm[0], nm[1], nm[2], nm[3]);
        *(float4*)&o_mem[idx + 4]  = make_float4(nm[4], nm[5], nm[6], nm[7]);
        *(float4*)&o_th[idx]       = make_float4(nt[0], nt[1], nt[2], nt[3]);
        *(float4*)&o_th[idx + 4]   = make_float4(nt[4], nt[5], nt[6], nt[7]);
        *(float4*)&o_post[idx]     = make_float4(np[0], np[1], np[2], np[3]);
        *(float4*)&o_post[idx + 4] = make_float4(np[4], np[5], np[6], np[7]);
    }
}

// ---------------------------------------------------------------------------
// K2: new_pre = clip(trace_pre*0.95 + in_spikes, 0, 1), vectorized float4
// ---------------------------------------------------------------------------
__global__ void k_pre(const float* __restrict__ xin, const float* __restrict__ tpre,
                      float* __restrict__ o_pre)
{
    const int i0 = blockIdx.x * 256 + threadIdx.x;  // 524288 threads
    const float4* x4 = (const float4*)xin;
    const float4* t4 = (const float4*)tpre;
    float4* o4 = (float4*)o_pre;
#pragma unroll
    for (int j = 0; j < 8; ++j) {
        const int i = i0 + j * 524288;
        const float4 x = x4[i];
        const float4 t = t4[i];
        float4 r;
        r.x = fminf(fmaxf(t.x * TR_DECAY + x.x, 0.f), 1.f);
        r.y = fminf(fmaxf(t.y * TR_DECAY + x.y, 0.f), 1.f);
        r.z = fminf(fmaxf(t.z * TR_DECAY + x.z, 0.f), 1.f);
        r.w = fminf(fmaxf(t.w * TR_DECAY + x.w, 0.f), 1.f);
        o4[i] = r;
    }
}

// ---------------------------------------------------------------------------
// K3: batch means of new_pre / new_post -> avg_pre, avg_post (C,H,W)
// ---------------------------------------------------------------------------
__global__ void k_avg(const float* __restrict__ pre, const float* __restrict__ post,
                      float* __restrict__ avg_pre, float* __restrict__ avg_post)
{
    const int i = blockIdx.x * 256 + threadIdx.x;   // 0..262143
    float s1 = 0.f, s2 = 0.f;
    for (int b = 0; b < BB; ++b) {
        s1 += pre[b * CHW + i];
        s2 += post[b * CHW + i];
    }
    avg_pre[i]  = s1 * (1.f / 64.f);
    avg_post[i] = s2 * (1.f / 64.f);
}

// ---------------------------------------------------------------------------
// K4: delta[c,3,3] = A_POS*corr(avg_post, avg_pre) - A_NEG*corr(avg_post, avg_post)
//     new_w = clip(w + delta_broadcast, +-0.1).  One block per channel c.
// ---------------------------------------------------------------------------
__global__ __launch_bounds__(256) void k_wupd(const float* __restrict__ avg_pre,
                                              const float* __restrict__ avg_post,
                                              const float* __restrict__ wgt,
                                              float* __restrict__ o_w)
{
    __shared__ float sp[4096];
    __shared__ float sq[66 * 66];
    __shared__ float sacc[18];
    __shared__ float sdelta[9];
    const int c = blockIdx.x, tid = threadIdx.x;

    for (int t = tid; t < 66 * 66; t += 256) sq[t] = 0.f;
    if (tid < 18) sacc[tid] = 0.f;
    __syncthreads();
    for (int t = tid; t < 4096; t += 256) {
        sp[t] = avg_pre[c * HW + t];
        sq[((t >> 6) + 1) * 66 + (t & 63) + 1] = avg_post[c * HW + t];
    }
    __syncthreads();

    float pot[9] = {0,0,0,0,0,0,0,0,0};
    float dep[9] = {0,0,0,0,0,0,0,0,0};
    for (int t = tid; t < 4096; t += 256) {
        const int yy = t >> 6, xx = t & 63;
        const float p = sp[t];
        const float q = sq[(yy + 1) * 66 + xx + 1];
#pragma unroll
        for (int dy = 0; dy < 3; ++dy)
#pragma unroll
            for (int dx = 0; dx < 3; ++dx) {
                const float v = sq[(yy + dy) * 66 + xx + dx];
                pot[dy * 3 + dx] += v * p;
                dep[dy * 3 + dx] += v * q;
            }
    }
#pragma unroll
    for (int k = 0; k < 18; ++k) {
        float v = (k < 9) ? pot[k] : dep[k - 9];
        for (int off = 32; off > 0; off >>= 1) v += __shfl_down(v, off, 64);
        if ((tid & 63) == 0) atomicAdd(&sacc[k], v);
    }
    __syncthreads();
    if (tid < 9) sdelta[tid] = A_POS * sacc[tid] - A_NEG * sacc[tid + 9];
    __syncthreads();
    for (int t = tid; t < 576; t += 256) {
        const float v = wgt[c * 576 + t] + sdelta[t % 9];
        o_w[c * 576 + t] = fminf(fmaxf(v, -W_CLIP), W_CLIP);
    }
}

// ---------------------------------------------------------------------------
extern "C" void kernel_launch(void* const* d_in, const int* in_sizes, int n_in,
                              void* d_out, int out_size, void* d_ws, size_t ws_size,
                              hipStream_t stream)
{
    const float* xin   = (const float*)d_in[0];
    const float* wgt   = (const float*)d_in[1];
    const float* mem   = (const float*)d_in[2];
    const float* th    = (const float*)d_in[3];
    const float* tpre  = (const float*)d_in[4];
    const float* tpost = (const float*)d_in[5];

    float* out    = (float*)d_out;
    float* o_spk  = out;
    float* o_mem  = out + (size_t)1 * NTOT;
    float* o_th   = out + (size_t)2 * NTOT;
    float* o_pre  = out + (size_t)3 * NTOT;
    float* o_post = out + (size_t)4 * NTOT;
    float* o_w    = out + (size_t)5 * NTOT;

    float* wt       = (float*)d_ws;          // 49152 floats
    float* avg_pre  = wt + 49152;            // 262144 floats
    float* avg_post = avg_pre + 262144;      // 262144 floats

    hipLaunchKernelGGL(k_transpose_w, dim3(144), dim3(256), 0, stream, wgt, wt);
    hipLaunchKernelGGL(k_conv_lif, dim3(1024), dim3(256), 0, stream,
                       xin, wt, mem, th, tpost, o_spk, o_mem, o_th, o_post);
    hipLaunchKernelGGL(k_pre, dim3(2048), dim3(256), 0, stream, xin, tpre, o_pre);
    hipLaunchKernelGGL(k_avg, dim3(1024), dim3(256), 0, stream, o_pre, o_post, avg_pre, avg_post);
    hipLaunchKernelGGL(k_wupd, dim3(64), dim3(256), 0, stream, avg_pre, avg_post, wgt, o_w);
}

// Round 3
// 615.913 us; speedup vs baseline: 1.4633x; 1.4633x over previous
//
#include <hip/hip_runtime.h>

typedef __attribute__((ext_vector_type(8))) short bf16x8;
typedef __attribute__((ext_vector_type(16))) float f32x16;

namespace {
constexpr int BB   = 64;
constexpr int CC   = 64;
constexpr int HH   = 64;
constexpr int WW   = 64;
constexpr int HW   = HH * WW;   // 4096
constexpr int CHW  = CC * HW;   // 262144
constexpr int NTOT = BB * CHW;  // 16777216
}

__device__ __forceinline__ ushort f2bf(float f) {
    union { float f; unsigned u; } x; x.f = f;
    unsigned r = x.u + 0x7fffu + ((x.u >> 16) & 1u);   // RNE
    return (ushort)(r >> 16);
}

__device__ __forceinline__ f32x16 zero16() {
    f32x16 z;
#pragma unroll
    for (int i = 0; i < 16; ++i) z[i] = 0.f;
    return z;
}

// ---------------------------------------------------------------------------
// K0: pack weights fp32 [co][ci][3][3] -> bf16 A-fragment image.
// Image: [dx][s=dy*4+ci16][gp][co][8ci]  (granule = 8 consecutive ci = 16B)
// A-frag read in K1: lane l: co = tile + (l&31), k = 8*(l>>5)+j, kstep s.
// ---------------------------------------------------------------------------
__global__ void k_prep_w(const float* __restrict__ w, ushort* __restrict__ wimg)
{
    const int e = blockIdx.x * 256 + threadIdx.x;     // 0..36863
    if (e >= 36864) return;
    const int ci07 = e & 7;
    const int co   = (e >> 3) & 63;
    const int gidx = e >> 9;          // 0..71 = dx*24 + s*2 + gp
    const int gp   = gidx & 1;
    const int s    = (gidx >> 1) % 12;
    const int dx   = gidx / 24;
    const int dy   = s >> 2;
    const int ci   = (s & 3) * 16 + gp * 8 + ci07;
    wimg[e] = f2bf(w[((co * 64 + ci) * 3 + dy) * 3 + dx]);
}

// ---------------------------------------------------------------------------
// K1: implicit-GEMM conv3x3 (bf16 MFMA) + LIF + new_pre + new_post.
// Block: 4 waves, (b, 4-row strip). Wave w: co-half = w>>1, x-half = w&1,
// computes 32co x 32x for all 4 rows via v_mfma_f32_32x32x16_bf16.
// K = (ci,dy) = 192 per dx pass; dx in {0,1,2} shifts B n-base by dx-1.
// LDS: in_lds[6 rows][66 n][64 ci] bf16, 16B-granule XOR-swizzled by n&7;
//      w_lds = one dx slab of the W image (24.6 KB).  Total 75.3 KB -> 2 blk/CU.
// ---------------------------------------------------------------------------
__global__ __launch_bounds__(256, 2) void k_conv_lif(
    const float* __restrict__ xin, const ushort* __restrict__ wimg,
    const float* __restrict__ membrane, const float* __restrict__ thresh,
    const float* __restrict__ tpre, const float* __restrict__ tpost,
    float* __restrict__ o_spk, float* __restrict__ o_mem, float* __restrict__ o_th,
    float* __restrict__ o_pre, float* __restrict__ o_post)
{
    __shared__ __align__(16) short in_lds[6 * 66 * 64];   // 50688 B
    __shared__ __align__(16) short w_lds[1536 * 8];       // 24576 B

    const int tid = threadIdx.x;
    const int b   = blockIdx.x >> 4;
    const int y0  = (blockIdx.x & 15) << 2;

    // ---- stage input strip rows y0-1..y0+4 (bf16, swizzled) + fused new_pre ----
    for (int it = tid; it < 3168; it += 256) {            // 6r * 8g * 66n
        const int n  = it % 66;
        const int t2 = it / 66;
        const int g  = t2 & 7;
        const int r  = t2 >> 3;
        const int gx = n - 1;
        const int gy = y0 + r - 1;
        const bool inb = ((unsigned)gx < 64u) && ((unsigned)gy < 64u);
        const int base = ((b * 64 + g * 8) * 64 + gy) * 64 + gx;
        float v[8];
#pragma unroll
        for (int j = 0; j < 8; ++j) {
            float f = 0.f;
            if (inb) f = xin[base + j * 4096];
            v[j] = f;
        }
        bf16x8 hv;
#pragma unroll
        for (int j = 0; j < 8; ++j) hv[j] = (short)f2bf(v[j]);
        *(bf16x8*)&in_lds[(r * 66 + n) * 64 + ((g ^ (n & 7)) << 3)] = hv;
        if (r >= 1 && r <= 4 && inb) {                    // rows owned by this block
#pragma unroll
            for (int j = 0; j < 8; ++j) {
                const float q = tpre[base + j * 4096] * 0.95f + v[j];
                o_pre[base + j * 4096] = fminf(fmaxf(q, 0.f), 1.f);
            }
        }
    }
    // ---- stage W slab dx=0 ----
    for (int i = tid; i < 1536; i += 256)
        *(bf16x8*)&w_lds[i * 8] = *(const bf16x8*)&wimg[i * 8];
    __syncthreads();

    const int wv = tid >> 6, ln = tid & 63;
    const int ch = wv >> 1, xh = wv & 1;
    const int lh = ln >> 5, l5 = ln & 31;

    f32x16 acc0 = zero16(), acc1 = zero16(), acc2 = zero16(), acc3 = zero16();

    for (int dx = 0; dx < 3; ++dx) {
        if (dx) {
            __syncthreads();
            for (int i = tid; i < 1536; i += 256)
                *(bf16x8*)&w_lds[i * 8] = *(const bf16x8*)&wimg[dx * 12288 + i * 8];
            __syncthreads();
        }
        const int nsl = xh * 32 + l5 + dx;    // B column slot (0..65)
        const int n7  = nsl & 7;
#pragma unroll
        for (int s = 0; s < 12; ++s) {
            const bf16x8 a = *(const bf16x8*)&w_lds[(((s * 2 + lh) * 64) + ch * 32 + l5) * 8];
            const int dy   = s >> 2;
            const int gsw  = (2 * (s & 3) + lh) ^ n7;
            const int boff = (dy * 66 + nsl) * 64 + (gsw << 3);
            acc0 = __builtin_amdgcn_mfma_f32_32x32x16_bf16(
                       a, *(const bf16x8*)&in_lds[boff           ], acc0, 0, 0, 0);
            acc1 = __builtin_amdgcn_mfma_f32_32x32x16_bf16(
                       a, *(const bf16x8*)&in_lds[boff + 1*66*64], acc1, 0, 0, 0);
            acc2 = __builtin_amdgcn_mfma_f32_32x32x16_bf16(
                       a, *(const bf16x8*)&in_lds[boff + 2*66*64], acc2, 0, 0, 0);
            acc3 = __builtin_amdgcn_mfma_f32_32x32x16_bf16(
                       a, *(const bf16x8*)&in_lds[boff + 3*66*64], acc3, 0, 0, 0);
        }
    }

    // ---- LIF epilogue: C/D layout col=lane&31 -> x, row=(r&3)+8*(r>>2)+4*lh -> co
    const int x = xh * 32 + l5;
#define EPILOG(ACC, Y)                                                          \
    {                                                                           \
        const int gy = y0 + (Y);                                                \
        _Pragma("unroll")                                                       \
        for (int rr = 0; rr < 16; ++rr) {                                       \
            const int co  = ch * 32 + (rr & 3) + 8 * (rr >> 2) + 4 * lh;        \
            const int idx = ((b * 64 + co) * 64 + gy) * 64 + x;                 \
            const float mem = membrane[idx] * 0.99f + (ACC)[rr];                \
            const float tv  = thresh[idx];                                      \
            const float sp  = (mem > tv) ? 1.f : 0.f;                           \
            o_spk[idx] = sp;                                                    \
            o_mem[idx] = (sp > 0.f) ? 0.1f : mem;                               \
            o_th[idx]  = (sp > 0.f) ? 1.0f : tv * 0.95f;                        \
            const float q = tpost[idx] * 0.95f + sp;                            \
            o_post[idx] = fminf(fmaxf(q, 0.f), 1.f);                            \
        }                                                                       \
    }
    EPILOG(acc0, 0)
    EPILOG(acc1, 1)
    EPILOG(acc2, 2)
    EPILOG(acc3, 3)
#undef EPILOG
}

// ---------------------------------------------------------------------------
// K2: batch means of new_pre / new_post (float4-vectorized)
// ---------------------------------------------------------------------------
__global__ void k_avg(const float4* __restrict__ pre, const float4* __restrict__ post,
                      float4* __restrict__ apre, float4* __restrict__ apost)
{
    const int i = blockIdx.x * 256 + threadIdx.x;   // 0..65535 (CHW/4)
    float4 s1 = make_float4(0.f, 0.f, 0.f, 0.f);
    float4 s2 = make_float4(0.f, 0.f, 0.f, 0.f);
    for (int bb = 0; bb < BB; ++bb) {
        const float4 p = pre[bb * (CHW / 4) + i];
        const float4 q = post[bb * (CHW / 4) + i];
        s1.x += p.x; s1.y += p.y; s1.z += p.z; s1.w += p.w;
        s2.x += q.x; s2.y += q.y; s2.z += q.z; s2.w += q.w;
    }
    const float sc = 1.f / 64.f;
    apre[i]  = make_float4(s1.x * sc, s1.y * sc, s1.z * sc, s1.w * sc);
    apost[i] = make_float4(s2.x * sc, s2.y * sc, s2.z * sc, s2.w * sc);
}

// ---------------------------------------------------------------------------
// K3: delta[c,3,3] = A_POS*corr(avg_post,avg_pre) - A_NEG*corr(avg_post,avg_post)
//     new_w = clip(w + delta, +-0.1). One block per channel.
// ---------------------------------------------------------------------------
__global__ __launch_bounds__(256) void k_wupd(const float* __restrict__ avg_pre,
                                              const float* __restrict__ avg_post,
                                              const float* __restrict__ wgt,
                                              float* __restrict__ o_w)
{
    __shared__ float sp[4096];
    __shared__ float sq[66 * 66];
    __shared__ float sacc[18];
    __shared__ float sdelta[9];
    const int c = blockIdx.x, tid = threadIdx.x;

    for (int t = tid; t < 66 * 66; t += 256) sq[t] = 0.f;
    if (tid < 18) sacc[tid] = 0.f;
    __syncthreads();
    for (int t = tid; t < 4096; t += 256) {
        sp[t] = avg_pre[c * HW + t];
        sq[((t >> 6) + 1) * 66 + (t & 63) + 1] = avg_post[c * HW + t];
    }
    __syncthreads();

    float pot[9] = {0,0,0,0,0,0,0,0,0};
    float dep[9] = {0,0,0,0,0,0,0,0,0};
    for (int t = tid; t < 4096; t += 256) {
        const int yy = t >> 6, xx = t & 63;
        const float p = sp[t];
        const float q = sq[(yy + 1) * 66 + xx + 1];
#pragma unroll
        for (int dy = 0; dy < 3; ++dy)
#pragma unroll
            for (int dxx = 0; dxx < 3; ++dxx) {
                const float v = sq[(yy + dy) * 66 + xx + dxx];
                pot[dy * 3 + dxx] += v * p;
                dep[dy * 3 + dxx] += v * q;
            }
    }
#pragma unroll
    for (int k = 0; k < 18; ++k) {
        float v = (k < 9) ? pot[k] : dep[k - 9];
        for (int off = 32; off > 0; off >>= 1) v += __shfl_down(v, off, 64);
        if ((tid & 63) == 0) atomicAdd(&sacc[k], v);
    }
    __syncthreads();
    if (tid < 9) sdelta[tid] = 0.005f * sacc[tid] - 0.005f * sacc[tid + 9];
    __syncthreads();
    for (int t = tid; t < 576; t += 256) {
        const float v = wgt[c * 576 + t] + sdelta[t % 9];
        o_w[c * 576 + t] = fminf(fmaxf(v, -0.1f), 0.1f);
    }
}

// ---------------------------------------------------------------------------
extern "C" void kernel_launch(void* const* d_in, const int* in_sizes, int n_in,
                              void* d_out, int out_size, void* d_ws, size_t ws_size,
                              hipStream_t stream)
{
    const float* xin   = (const float*)d_in[0];
    const float* wgt   = (const float*)d_in[1];
    const float* mem   = (const float*)d_in[2];
    const float* th    = (const float*)d_in[3];
    const float* tpre  = (const float*)d_in[4];
    const float* tpost = (const float*)d_in[5];

    float* out    = (float*)d_out;
    float* o_spk  = out;
    float* o_mem  = out + (size_t)1 * NTOT;
    float* o_th   = out + (size_t)2 * NTOT;
    float* o_pre  = out + (size_t)3 * NTOT;
    float* o_post = out + (size_t)4 * NTOT;
    float* o_w    = out + (size_t)5 * NTOT;

    ushort* wimg    = (ushort*)d_ws;                       // 36864 ushort = 73728 B
    float* avg_pre  = (float*)((char*)d_ws + 73728);       // 262144 floats
    float* avg_post = avg_pre + CHW;                       // 262144 floats

    hipLaunchKernelGGL(k_prep_w, dim3(144), dim3(256), 0, stream, wgt, wimg);
    hipLaunchKernelGGL(k_conv_lif, dim3(1024), dim3(256), 0, stream,
                       xin, wimg, mem, th, tpre, tpost,
                       o_spk, o_mem, o_th, o_pre, o_post);
    hipLaunchKernelGGL(k_avg, dim3(256), dim3(256), 0, stream,
                       (const float4*)o_pre, (const float4*)o_post,
                       (float4*)avg_pre, (float4*)avg_post);
    hipLaunchKernelGGL(k_wupd, dim3(64), dim3(256), 0, stream,
                       avg_pre, avg_post, wgt, o_w);
}